// Round 8
// baseline (314.104 us; speedup 1.0000x reference)
//
#include <hip/hip_runtime.h>
#include <cstddef>

#define ZDIM 64
#define PDIM 4096          // Z*Z
#define PB   256           // p's per block (= blockDim)
#define BCHUNK 16          // batch rows per block (8 row-pairs, fully unrolled)
#define NPAIR (BCHUNK/2)

typedef float v2f __attribute__((ext_vector_type(2)));

__device__ __forceinline__ v2f pkfma(v2f a, v2f b, v2f c) {
    return __builtin_elementwise_fma(a, b, c);
}
__device__ __forceinline__ v2f splat(float s) { v2f r; r.x = s; r.y = s; return r; }

__device__ __forceinline__ float rfl(float v) {
    return __int_as_float(__builtin_amdgcn_readfirstlane(__float_as_int(v)));
}

// Odd Pade(5,4) tanh: x(945+105t+t^2)/(945+420t+15t^2), t=x^2.
// Validated R7 (absmax 0.0039, threshold 0.0147).
__device__ __forceinline__ v2f tanh54(v2f x) {
    v2f t = x * x;
    v2f num = x * pkfma(t, t + splat(105.0f), splat(945.0f));
    v2f den = pkfma(pkfma(splat(15.0f), t, splat(420.0f)), t, splat(945.0f));
    v2f r; r.x = __builtin_amdgcn_rcpf(den.x); r.y = __builtin_amdgcn_rcpf(den.y);
    return num * r;
}

__global__ void __launch_bounds__(PB, 8) pair_mlp_kernel(
    const float* __restrict__ x,
    const float* __restrict__ W1, const float* __restrict__ b1,
    const float* __restrict__ g1, const float* __restrict__ be1,
    const float* __restrict__ W2, const float* __restrict__ b2,
    const float* __restrict__ g2, const float* __restrict__ be2,
    const float* __restrict__ W3, const float* __restrict__ b3,
    float* __restrict__ out, int nbc)
{
    const int tid = threadIdx.x;
    const int pb  = blockIdx.x / nbc;          // p-tile (0..15)
    const int bc  = blockIdx.x - pb * nbc;     // batch chunk
    const int p   = pb * PB + tid;
    const int z   = __builtin_amdgcn_readfirstlane(p >> 6);  // wave-uniform
    const int zp  = p & 63;
    const int b0  = bc * BCHUNK;

    // -------- stage x chunk (16 rows x 64) into LDS --------
    __shared__ float xs[BCHUNK * ZDIM];   // 4 KB
    {
        const float4* xg = reinterpret_cast<const float4*>(x + (size_t)b0 * ZDIM);
        reinterpret_cast<float4*>(xs)[tid] = xg[tid];   // 1024 floats, coalesced
    }

    // -------- a-side: wave-uniform x values -> SGPRs (readfirstlane) --------
    const float* xrow = x + (size_t)b0 * ZDIM;
    float avr[BCHUNK];
    #pragma unroll
    for (int r = 0; r < BCHUNK; ++r)
        avr[r] = rfl(xrow[r * ZDIM + z]);

    // ---------------- load per-p weights ----------------
    const float4* W1v = reinterpret_cast<const float4*>(W1 + (size_t)p * 8);
    const float4 w1x = W1v[0];
    const float4 w1y = W1v[1];
    const float4 b1v  = reinterpret_cast<const float4*>(b1)[p];
    const float4 g1v  = reinterpret_cast<const float4*>(g1)[p];
    const float4 be1v = reinterpret_cast<const float4*>(be1)[p];
    float w2[4][4];
    {
        const float4* W2v = reinterpret_cast<const float4*>(W2 + (size_t)p * 16);
        #pragma unroll
        for (int i = 0; i < 4; ++i) {
            float4 r = W2v[i];
            w2[i][0] = r.x; w2[i][1] = r.y; w2[i][2] = r.z; w2[i][3] = r.w;
        }
    }
    const float4 b2v  = reinterpret_cast<const float4*>(b2)[p];
    const float4 g2v  = reinterpret_cast<const float4*>(g2)[p];
    const float4 be2v = reinterpret_cast<const float4*>(be2)[p];
    const float4 w3v  = reinterpret_cast<const float4*>(W3)[p];
    const float  b3s  = b3[p];

    const float w1a[4] = {w1x.x, w1x.y, w1x.z, w1x.w};
    const float w1b[4] = {w1y.x, w1y.y, w1y.z, w1y.w};
    const float b1a[4] = {b1v.x, b1v.y, b1v.z, b1v.w};
    const float g1a[4] = {g1v.x, g1v.y, g1v.z, g1v.w};
    const float be1a[4]= {be1v.x, be1v.y, be1v.z, be1v.w};
    const float b2a[4] = {b2v.x, b2v.y, b2v.z, b2v.w};
    const float g2a[4] = {g2v.x, g2v.y, g2v.z, g2v.w};
    const float be2a[4]= {be2v.x, be2v.y, be2v.z, be2v.w};
    const float w3a[4] = {w3v.x, w3v.y, w3v.z, w3v.w};

    // ---- fold LN1 affine into layer 2, LN2 affine into layer 3 (centered) ----
    float w2g[4][4], b2p[4];
    #pragma unroll
    for (int j = 0; j < 4; ++j) b2p[j] = b2a[j];
    #pragma unroll
    for (int i = 0; i < 4; ++i) {
        #pragma unroll
        for (int j = 0; j < 4; ++j) {
            w2g[i][j] = g1a[i] * w2[i][j];
            b2p[j] = __builtin_fmaf(be1a[i], w2[i][j], b2p[j]);
        }
    }
    float w3g[4], b3p = b3s;
    #pragma unroll
    for (int j = 0; j < 4; ++j) {
        w3g[j] = g2a[j] * w3a[j];
        b3p = __builtin_fmaf(be2a[j], w3a[j], b3p);
    }

    float* obase = out + (size_t)b0 * PDIM + p;

    __syncthreads();   // xs ready

    // ---------------- fully unrolled: 8 row-pairs ----------------
    #pragma unroll
    for (int k = 0; k < NPAIR; ++k) {
        v2f a2, c2;
        a2.x = avr[2 * k]; a2.y = avr[2 * k + 1];   // from SGPRs
        c2.x = xs[(2 * k) * ZDIM + zp];             // DS pipe
        c2.y = xs[(2 * k + 1) * ZDIM + zp];

        // layer 1 + tanh
        v2f t0 = tanh54(pkfma(a2, splat(w1a[0]), pkfma(c2, splat(w1b[0]), splat(b1a[0]))));
        v2f t1 = tanh54(pkfma(a2, splat(w1a[1]), pkfma(c2, splat(w1b[1]), splat(b1a[1]))));
        v2f t2 = tanh54(pkfma(a2, splat(w1a[2]), pkfma(c2, splat(w1b[2]), splat(b1a[2]))));
        v2f t3 = tanh54(pkfma(a2, splat(w1a[3]), pkfma(c2, splat(w1b[3]), splat(b1a[3]))));

        // LN1: mean, centered variance
        v2f s1 = (t0 + t1) + (t2 + t3);
        v2f m  = s1 * 0.25f;
        v2f d0 = t0 - m, d1 = t1 - m, d2 = t2 - m, d3 = t3 - m;
        v2f sd = pkfma(d0, d0, pkfma(d1, d1, pkfma(d2, d2, d3 * d3)));
        v2f var = pkfma(sd, splat(0.25f), splat(1e-5f));
        v2f rs; rs.x = __builtin_amdgcn_rsqf(var.x); rs.y = __builtin_amdgcn_rsqf(var.y);

        // layer 2 (LN1 folded) + tanh
        v2f acc;
        acc = pkfma(d0, splat(w2g[0][0]), pkfma(d1, splat(w2g[1][0]), pkfma(d2, splat(w2g[2][0]), d3 * splat(w2g[3][0]))));
        v2f u0 = tanh54(pkfma(rs, acc, splat(b2p[0])));
        acc = pkfma(d0, splat(w2g[0][1]), pkfma(d1, splat(w2g[1][1]), pkfma(d2, splat(w2g[2][1]), d3 * splat(w2g[3][1]))));
        v2f u1 = tanh54(pkfma(rs, acc, splat(b2p[1])));
        acc = pkfma(d0, splat(w2g[0][2]), pkfma(d1, splat(w2g[1][2]), pkfma(d2, splat(w2g[2][2]), d3 * splat(w2g[3][2]))));
        v2f u2 = tanh54(pkfma(rs, acc, splat(b2p[2])));
        acc = pkfma(d0, splat(w2g[0][3]), pkfma(d1, splat(w2g[1][3]), pkfma(d2, splat(w2g[2][3]), d3 * splat(w2g[3][3]))));
        v2f u3 = tanh54(pkfma(rs, acc, splat(b2p[3])));

        // LN2: mean, centered variance
        v2f q1 = (u0 + u1) + (u2 + u3);
        v2f m2 = q1 * 0.25f;
        v2f e0 = u0 - m2, e1 = u1 - m2, e2 = u2 - m2, e3 = u3 - m2;
        v2f se = pkfma(e0, e0, pkfma(e1, e1, pkfma(e2, e2, e3 * e3)));
        v2f var2 = pkfma(se, splat(0.25f), splat(1e-5f));
        v2f rs2; rs2.x = __builtin_amdgcn_rsqf(var2.x); rs2.y = __builtin_amdgcn_rsqf(var2.y);

        // layer 3 (LN2 folded) + sigmoid (exp form)
        v2f acc3 = pkfma(e0, splat(w3g[0]), pkfma(e1, splat(w3g[1]), pkfma(e2, splat(w3g[2]), e3 * splat(w3g[3]))));
        v2f sarg = pkfma(rs2, acc3, splat(b3p));
        v2f q = sarg * splat(-1.4426950408889634f);
        v2f e; e.x = __builtin_amdgcn_exp2f(q.x); e.y = __builtin_amdgcn_exp2f(q.y);
        v2f ep1 = e + splat(1.0f);

        obase[(size_t)(2 * k) * PDIM]     = __builtin_amdgcn_rcpf(ep1.x);
        obase[(size_t)(2 * k + 1) * PDIM] = __builtin_amdgcn_rcpf(ep1.y);
    }
}

extern "C" void kernel_launch(void* const* d_in, const int* in_sizes, int n_in,
                              void* d_out, int out_size, void* d_ws, size_t ws_size,
                              hipStream_t stream) {
    const float* x   = (const float*)d_in[0];
    const float* W1  = (const float*)d_in[1];
    const float* b1  = (const float*)d_in[2];
    const float* g1  = (const float*)d_in[3];
    const float* be1 = (const float*)d_in[4];
    const float* W2  = (const float*)d_in[5];
    const float* b2  = (const float*)d_in[6];
    const float* g2  = (const float*)d_in[7];
    const float* be2 = (const float*)d_in[8];
    const float* W3  = (const float*)d_in[9];
    const float* b3  = (const float*)d_in[10];
    float* out = (float*)d_out;

    const int B   = in_sizes[0] / ZDIM;     // 4096
    const int nbc = B / BCHUNK;             // 256
    const int grid = (PDIM / PB) * nbc;     // 16 * 256 = 4096

    hipLaunchKernelGGL(pair_mlp_kernel, dim3(grid), dim3(PB), 0, stream,
                       x, W1, b1, g1, be1, W2, b2, g2, be2, W3, b3, out, nbc);
}

// Round 12
// 134.212 us; speedup vs baseline: 2.3404x; 2.3404x over previous
//
#include <hip/hip_runtime.h>
#include <cstddef>

#define ZDIM 64
#define PDIM 4096          // Z*Z
#define PB   256           // p's per block (= blockDim)
#define BCHUNK 32          // batch rows per block (16 row-pairs, fully unrolled)
#define NPAIR (BCHUNK/2)

typedef float v2f __attribute__((ext_vector_type(2)));

__device__ __forceinline__ v2f pkfma(v2f a, v2f b, v2f c) {
    return __builtin_elementwise_fma(a, b, c);
}
__device__ __forceinline__ v2f splat(float s) { v2f r; r.x = s; r.y = s; return r; }

__device__ __forceinline__ float rfl(float v) {
    return __int_as_float(__builtin_amdgcn_readfirstlane(__float_as_int(v)));
}

// Odd Pade(5,4) tanh: x(945+105t+t^2)/(945+420t+15t^2), t=x^2.
// Validated R7 (absmax 0.0039 = 1 bf16 ulp).
__device__ __forceinline__ v2f tanh54(v2f x) {
    v2f t = x * x;
    v2f num = x * pkfma(t, t + splat(105.0f), splat(945.0f));
    v2f den = pkfma(pkfma(splat(15.0f), t, splat(420.0f)), t, splat(945.0f));
    v2f r; r.x = __builtin_amdgcn_rcpf(den.x); r.y = __builtin_amdgcn_rcpf(den.y);
    return num * r;
}

__global__ void __launch_bounds__(PB) pair_mlp_kernel(
    const float* __restrict__ x,
    const float* __restrict__ W1, const float* __restrict__ b1,
    const float* __restrict__ g1, const float* __restrict__ be1,
    const float* __restrict__ W2, const float* __restrict__ b2,
    const float* __restrict__ g2, const float* __restrict__ be2,
    const float* __restrict__ W3, const float* __restrict__ b3,
    float* __restrict__ out, int nbc)
{
    const int tid = threadIdx.x;
    const int pb  = blockIdx.x / nbc;          // p-tile (0..15)
    const int bc  = blockIdx.x - pb * nbc;     // batch chunk
    const int p   = pb * PB + tid;
    const int z   = __builtin_amdgcn_readfirstlane(p >> 6);  // wave-uniform
    const int zp  = p & 63;
    const int b0  = bc * BCHUNK;

    // -------- stage x chunk (32 rows x 64) into LDS --------
    __shared__ float xs[BCHUNK * ZDIM];   // 8 KB
    {
        const float4* xg = reinterpret_cast<const float4*>(x + (size_t)b0 * ZDIM);
        float4* xs4 = reinterpret_cast<float4*>(xs);
        #pragma unroll
        for (int i = 0; i < (BCHUNK * ZDIM / 4) / PB; ++i)
            xs4[tid + i * PB] = xg[tid + i * PB];   // coalesced
    }

    // -------- a-side: wave-uniform x values -> SGPRs (readfirstlane) --------
    const float* xrow = x + (size_t)b0 * ZDIM;
    float avr[BCHUNK];
    #pragma unroll
    for (int r = 0; r < BCHUNK; ++r)
        avr[r] = rfl(xrow[r * ZDIM + z]);

    // ---------------- load per-p weights ----------------
    const float4* W1v = reinterpret_cast<const float4*>(W1 + (size_t)p * 8);
    const float4 w1x = W1v[0];
    const float4 w1y = W1v[1];
    const float4 b1v  = reinterpret_cast<const float4*>(b1)[p];
    const float4 g1v  = reinterpret_cast<const float4*>(g1)[p];
    const float4 be1v = reinterpret_cast<const float4*>(be1)[p];
    float w2[4][4];
    {
        const float4* W2v = reinterpret_cast<const float4*>(W2 + (size_t)p * 16);
        #pragma unroll
        for (int i = 0; i < 4; ++i) {
            float4 r = W2v[i];
            w2[i][0] = r.x; w2[i][1] = r.y; w2[i][2] = r.z; w2[i][3] = r.w;
        }
    }
    const float4 b2v  = reinterpret_cast<const float4*>(b2)[p];
    const float4 g2v  = reinterpret_cast<const float4*>(g2)[p];
    const float4 be2v = reinterpret_cast<const float4*>(be2)[p];
    const float4 w3v  = reinterpret_cast<const float4*>(W3)[p];
    const float  b3s  = b3[p];

    const float w1a[4] = {w1x.x, w1x.y, w1x.z, w1x.w};
    const float w1b[4] = {w1y.x, w1y.y, w1y.z, w1y.w};
    const float b1a[4] = {b1v.x, b1v.y, b1v.z, b1v.w};
    const float g1a[4] = {g1v.x, g1v.y, g1v.z, g1v.w};
    const float be1a[4]= {be1v.x, be1v.y, be1v.z, be1v.w};
    const float b2a[4] = {b2v.x, b2v.y, b2v.z, b2v.w};
    const float g2a[4] = {g2v.x, g2v.y, g2v.z, g2v.w};
    const float be2a[4]= {be2v.x, be2v.y, be2v.z, be2v.w};
    const float w3a[4] = {w3v.x, w3v.y, w3v.z, w3v.w};

    // ---- fold LN1 affine into layer 2, LN2 affine into layer 3 (centered) ----
    float w2g[4][4], b2p[4];
    #pragma unroll
    for (int j = 0; j < 4; ++j) b2p[j] = b2a[j];
    #pragma unroll
    for (int i = 0; i < 4; ++i) {
        #pragma unroll
        for (int j = 0; j < 4; ++j) {
            w2g[i][j] = g1a[i] * w2[i][j];
            b2p[j] = __builtin_fmaf(be1a[i], w2[i][j], b2p[j]);
        }
    }
    float w3g[4], b3p = b3s;
    #pragma unroll
    for (int j = 0; j < 4; ++j) {
        w3g[j] = g2a[j] * w3a[j];
        b3p = __builtin_fmaf(be2a[j], w3a[j], b3p);
    }

    float* obase = out + (size_t)b0 * PDIM + p;

    __syncthreads();   // xs ready

    // ---------------- fully unrolled: 16 row-pairs ----------------
    #pragma unroll
    for (int k = 0; k < NPAIR; ++k) {
        v2f a2, c2;
        a2.x = avr[2 * k]; a2.y = avr[2 * k + 1];   // from SGPRs
        c2.x = xs[(2 * k) * ZDIM + zp];             // DS pipe
        c2.y = xs[(2 * k + 1) * ZDIM + zp];

        // layer 1 + tanh
        v2f t0 = tanh54(pkfma(a2, splat(w1a[0]), pkfma(c2, splat(w1b[0]), splat(b1a[0]))));
        v2f t1 = tanh54(pkfma(a2, splat(w1a[1]), pkfma(c2, splat(w1b[1]), splat(b1a[1]))));
        v2f t2 = tanh54(pkfma(a2, splat(w1a[2]), pkfma(c2, splat(w1b[2]), splat(b1a[2]))));
        v2f t3 = tanh54(pkfma(a2, splat(w1a[3]), pkfma(c2, splat(w1b[3]), splat(b1a[3]))));

        // LN1: mean, centered variance
        v2f s1 = (t0 + t1) + (t2 + t3);
        v2f m  = s1 * 0.25f;
        v2f d0 = t0 - m, d1 = t1 - m, d2 = t2 - m, d3 = t3 - m;
        v2f sd = pkfma(d0, d0, pkfma(d1, d1, pkfma(d2, d2, d3 * d3)));
        v2f var = pkfma(sd, splat(0.25f), splat(1e-5f));
        v2f rs; rs.x = __builtin_amdgcn_rsqf(var.x); rs.y = __builtin_amdgcn_rsqf(var.y);

        // layer 2 (LN1 folded) + tanh
        v2f acc;
        acc = pkfma(d0, splat(w2g[0][0]), pkfma(d1, splat(w2g[1][0]), pkfma(d2, splat(w2g[2][0]), d3 * splat(w2g[3][0]))));
        v2f u0 = tanh54(pkfma(rs, acc, splat(b2p[0])));
        acc = pkfma(d0, splat(w2g[0][1]), pkfma(d1, splat(w2g[1][1]), pkfma(d2, splat(w2g[2][1]), d3 * splat(w2g[3][1]))));
        v2f u1 = tanh54(pkfma(rs, acc, splat(b2p[1])));
        acc = pkfma(d0, splat(w2g[0][2]), pkfma(d1, splat(w2g[1][2]), pkfma(d2, splat(w2g[2][2]), d3 * splat(w2g[3][2]))));
        v2f u2 = tanh54(pkfma(rs, acc, splat(b2p[2])));
        acc = pkfma(d0, splat(w2g[0][3]), pkfma(d1, splat(w2g[1][3]), pkfma(d2, splat(w2g[2][3]), d3 * splat(w2g[3][3]))));
        v2f u3 = tanh54(pkfma(rs, acc, splat(b2p[3])));

        // LN2: mean, centered variance
        v2f q1 = (u0 + u1) + (u2 + u3);
        v2f m2 = q1 * 0.25f;
        v2f e0 = u0 - m2, e1 = u1 - m2, e2 = u2 - m2, e3 = u3 - m2;
        v2f se = pkfma(e0, e0, pkfma(e1, e1, pkfma(e2, e2, e3 * e3)));
        v2f var2 = pkfma(se, splat(0.25f), splat(1e-5f));
        v2f rs2; rs2.x = __builtin_amdgcn_rsqf(var2.x); rs2.y = __builtin_amdgcn_rsqf(var2.y);

        // layer 3 (LN2 folded) + sigmoid (exp form)
        v2f acc3 = pkfma(e0, splat(w3g[0]), pkfma(e1, splat(w3g[1]), pkfma(e2, splat(w3g[2]), e3 * splat(w3g[3]))));
        v2f sarg = pkfma(rs2, acc3, splat(b3p));
        v2f q = sarg * splat(-1.4426950408889634f);
        v2f e; e.x = __builtin_amdgcn_exp2f(q.x); e.y = __builtin_amdgcn_exp2f(q.y);
        v2f ep1 = e + splat(1.0f);

        obase[(size_t)(2 * k) * PDIM]     = __builtin_amdgcn_rcpf(ep1.x);
        obase[(size_t)(2 * k + 1) * PDIM] = __builtin_amdgcn_rcpf(ep1.y);
    }
}

extern "C" void kernel_launch(void* const* d_in, const int* in_sizes, int n_in,
                              void* d_out, int out_size, void* d_ws, size_t ws_size,
                              hipStream_t stream) {
    const float* x   = (const float*)d_in[0];
    const float* W1  = (const float*)d_in[1];
    const float* b1  = (const float*)d_in[2];
    const float* g1  = (const float*)d_in[3];
    const float* be1 = (const float*)d_in[4];
    const float* W2  = (const float*)d_in[5];
    const float* b2  = (const float*)d_in[6];
    const float* g2  = (const float*)d_in[7];
    const float* be2 = (const float*)d_in[8];
    const float* W3  = (const float*)d_in[9];
    const float* b3  = (const float*)d_in[10];
    float* out = (float*)d_out;

    const int B   = in_sizes[0] / ZDIM;     // 4096
    const int nbc = B / BCHUNK;             // 128
    const int grid = (PDIM / PB) * nbc;     // 16 * 128 = 2048

    hipLaunchKernelGGL(pair_mlp_kernel, dim3(grid), dim3(PB), 0, stream,
                       x, W1, b1, g1, be1, W2, b2, g2, be2, W3, b3, out, nbc);
}

// Round 13
// 133.061 us; speedup vs baseline: 2.3606x; 1.0087x over previous
//
#include <hip/hip_runtime.h>
#include <cstddef>

#define ZDIM 64
#define PDIM 4096          // Z*Z
#define PB   64            // p's per block = 1 wave
#define BCHUNK 16          // batch rows per block (8 row-pairs, fully unrolled)
#define NPAIR (BCHUNK/2)

typedef float v2f __attribute__((ext_vector_type(2)));

__device__ __forceinline__ v2f pkfma(v2f a, v2f b, v2f c) {
    return __builtin_elementwise_fma(a, b, c);
}
__device__ __forceinline__ v2f splat(float s) { v2f r; r.x = s; r.y = s; return r; }

__device__ __forceinline__ float rfl(float v) {
    return __int_as_float(__builtin_amdgcn_readfirstlane(__float_as_int(v)));
}

// Odd Pade(5,4) tanh: x(945+105t+t^2)/(945+420t+15t^2), t=x^2.
// Validated R7/R12 (absmax 0.0039 = 1 bf16 ulp).
__device__ __forceinline__ v2f tanh54(v2f x) {
    v2f t = x * x;
    v2f num = x * pkfma(t, t + splat(105.0f), splat(945.0f));
    v2f den = pkfma(pkfma(splat(15.0f), t, splat(420.0f)), t, splat(945.0f));
    v2f r; r.x = __builtin_amdgcn_rcpf(den.x); r.y = __builtin_amdgcn_rcpf(den.y);
    return num * r;
}

__global__ void __launch_bounds__(PB) pair_mlp_kernel(
    const float* __restrict__ x,
    const float* __restrict__ W1, const float* __restrict__ b1,
    const float* __restrict__ g1, const float* __restrict__ be1,
    const float* __restrict__ W2, const float* __restrict__ b2,
    const float* __restrict__ g2, const float* __restrict__ be2,
    const float* __restrict__ W3, const float* __restrict__ b3,
    float* __restrict__ out, int nbc)
{
    const int tid = threadIdx.x;               // 0..63 == lane == zp
    const int pb  = blockIdx.x / nbc;          // p-tile (0..63)
    const int bc  = blockIdx.x - pb * nbc;     // batch chunk (0..255)
    const int p   = pb * PB + tid;
    const int z   = pb;                        // block-uniform: p>>6 == pb
    const int zp  = tid;
    const int b0  = bc * BCHUNK;

    // -------- stage x chunk (16 rows x 64) into LDS (intra-wave, no barrier) --------
    __shared__ float xs[BCHUNK * ZDIM];   // 4 KB
    {
        const float4* xg = reinterpret_cast<const float4*>(x + (size_t)b0 * ZDIM);
        float4* xs4 = reinterpret_cast<float4*>(xs);
        #pragma unroll
        for (int i = 0; i < (BCHUNK * ZDIM / 4) / PB; ++i)
            xs4[tid + i * PB] = xg[tid + i * PB];   // coalesced
    }

    // -------- a-side: wave-uniform x values -> SGPRs (readfirstlane) --------
    const float* xrow = x + (size_t)b0 * ZDIM;
    float avr[BCHUNK];
    #pragma unroll
    for (int r = 0; r < BCHUNK; ++r)
        avr[r] = rfl(xrow[r * ZDIM + z]);

    // ---------------- load per-p weights ----------------
    const float4* W1v = reinterpret_cast<const float4*>(W1 + (size_t)p * 8);
    const float4 w1x = W1v[0];
    const float4 w1y = W1v[1];
    const float4 b1v  = reinterpret_cast<const float4*>(b1)[p];
    const float4 g1v  = reinterpret_cast<const float4*>(g1)[p];
    const float4 be1v = reinterpret_cast<const float4*>(be1)[p];
    float w2[4][4];
    {
        const float4* W2v = reinterpret_cast<const float4*>(W2 + (size_t)p * 16);
        #pragma unroll
        for (int i = 0; i < 4; ++i) {
            float4 r = W2v[i];
            w2[i][0] = r.x; w2[i][1] = r.y; w2[i][2] = r.z; w2[i][3] = r.w;
        }
    }
    const float4 b2v  = reinterpret_cast<const float4*>(b2)[p];
    const float4 g2v  = reinterpret_cast<const float4*>(g2)[p];
    const float4 be2v = reinterpret_cast<const float4*>(be2)[p];
    const float4 w3v  = reinterpret_cast<const float4*>(W3)[p];
    const float  b3s  = b3[p];

    const float w1a[4] = {w1x.x, w1x.y, w1x.z, w1x.w};
    const float w1b[4] = {w1y.x, w1y.y, w1y.z, w1y.w};
    const float b1a[4] = {b1v.x, b1v.y, b1v.z, b1v.w};
    const float g1a[4] = {g1v.x, g1v.y, g1v.z, g1v.w};
    const float be1a[4]= {be1v.x, be1v.y, be1v.z, be1v.w};
    const float b2a[4] = {b2v.x, b2v.y, b2v.z, b2v.w};
    const float g2a[4] = {g2v.x, g2v.y, g2v.z, g2v.w};
    const float be2a[4]= {be2v.x, be2v.y, be2v.z, be2v.w};
    const float w3a[4] = {w3v.x, w3v.y, w3v.z, w3v.w};

    // ---- fold LN1 affine into layer 2, LN2 affine into layer 3 (centered) ----
    float w2g[4][4], b2p[4];
    #pragma unroll
    for (int j = 0; j < 4; ++j) b2p[j] = b2a[j];
    #pragma unroll
    for (int i = 0; i < 4; ++i) {
        #pragma unroll
        for (int j = 0; j < 4; ++j) {
            w2g[i][j] = g1a[i] * w2[i][j];
            b2p[j] = __builtin_fmaf(be1a[i], w2[i][j], b2p[j]);
        }
    }
    float w3g[4], b3p = b3s;
    #pragma unroll
    for (int j = 0; j < 4; ++j) {
        w3g[j] = g2a[j] * w3a[j];
        b3p = __builtin_fmaf(be2a[j], w3a[j], b3p);
    }

    float* obase = out + (size_t)b0 * PDIM + p;

    // ---------------- fully unrolled: 8 row-pairs ----------------
    #pragma unroll
    for (int k = 0; k < NPAIR; ++k) {
        v2f a2, c2;
        a2.x = avr[2 * k]; a2.y = avr[2 * k + 1];   // from SGPRs
        c2.x = xs[(2 * k) * ZDIM + zp];             // DS pipe, conflict-free
        c2.y = xs[(2 * k + 1) * ZDIM + zp];

        // layer 1 + tanh
        v2f t0 = tanh54(pkfma(a2, splat(w1a[0]), pkfma(c2, splat(w1b[0]), splat(b1a[0]))));
        v2f t1 = tanh54(pkfma(a2, splat(w1a[1]), pkfma(c2, splat(w1b[1]), splat(b1a[1]))));
        v2f t2 = tanh54(pkfma(a2, splat(w1a[2]), pkfma(c2, splat(w1b[2]), splat(b1a[2]))));
        v2f t3 = tanh54(pkfma(a2, splat(w1a[3]), pkfma(c2, splat(w1b[3]), splat(b1a[3]))));

        // LN1: mean, centered variance
        v2f s1 = (t0 + t1) + (t2 + t3);
        v2f m  = s1 * 0.25f;
        v2f d0 = t0 - m, d1 = t1 - m, d2 = t2 - m, d3 = t3 - m;
        v2f sd = pkfma(d0, d0, pkfma(d1, d1, pkfma(d2, d2, d3 * d3)));
        v2f var = pkfma(sd, splat(0.25f), splat(1e-5f));
        v2f rs; rs.x = __builtin_amdgcn_rsqf(var.x); rs.y = __builtin_amdgcn_rsqf(var.y);

        // layer 2 (LN1 folded) + tanh
        v2f acc;
        acc = pkfma(d0, splat(w2g[0][0]), pkfma(d1, splat(w2g[1][0]), pkfma(d2, splat(w2g[2][0]), d3 * splat(w2g[3][0]))));
        v2f u0 = tanh54(pkfma(rs, acc, splat(b2p[0])));
        acc = pkfma(d0, splat(w2g[0][1]), pkfma(d1, splat(w2g[1][1]), pkfma(d2, splat(w2g[2][1]), d3 * splat(w2g[3][1]))));
        v2f u1 = tanh54(pkfma(rs, acc, splat(b2p[1])));
        acc = pkfma(d0, splat(w2g[0][2]), pkfma(d1, splat(w2g[1][2]), pkfma(d2, splat(w2g[2][2]), d3 * splat(w2g[3][2]))));
        v2f u2 = tanh54(pkfma(rs, acc, splat(b2p[2])));
        acc = pkfma(d0, splat(w2g[0][3]), pkfma(d1, splat(w2g[1][3]), pkfma(d2, splat(w2g[2][3]), d3 * splat(w2g[3][3]))));
        v2f u3 = tanh54(pkfma(rs, acc, splat(b2p[3])));

        // LN2: mean, centered variance
        v2f q1 = (u0 + u1) + (u2 + u3);
        v2f m2 = q1 * 0.25f;
        v2f e0 = u0 - m2, e1 = u1 - m2, e2 = u2 - m2, e3 = u3 - m2;
        v2f se = pkfma(e0, e0, pkfma(e1, e1, pkfma(e2, e2, e3 * e3)));
        v2f var2 = pkfma(se, splat(0.25f), splat(1e-5f));
        v2f rs2; rs2.x = __builtin_amdgcn_rsqf(var2.x); rs2.y = __builtin_amdgcn_rsqf(var2.y);

        // layer 3 (LN2 folded) + sigmoid (exp form)
        v2f acc3 = pkfma(e0, splat(w3g[0]), pkfma(e1, splat(w3g[1]), pkfma(e2, splat(w3g[2]), e3 * splat(w3g[3]))));
        v2f sarg = pkfma(rs2, acc3, splat(b3p));
        v2f q = sarg * splat(-1.4426950408889634f);
        v2f e; e.x = __builtin_amdgcn_exp2f(q.x); e.y = __builtin_amdgcn_exp2f(q.y);
        v2f ep1 = e + splat(1.0f);

        obase[(size_t)(2 * k) * PDIM]     = __builtin_amdgcn_rcpf(ep1.x);
        obase[(size_t)(2 * k + 1) * PDIM] = __builtin_amdgcn_rcpf(ep1.y);
    }
}

extern "C" void kernel_launch(void* const* d_in, const int* in_sizes, int n_in,
                              void* d_out, int out_size, void* d_ws, size_t ws_size,
                              hipStream_t stream) {
    const float* x   = (const float*)d_in[0];
    const float* W1  = (const float*)d_in[1];
    const float* b1  = (const float*)d_in[2];
    const float* g1  = (const float*)d_in[3];
    const float* be1 = (const float*)d_in[4];
    const float* W2  = (const float*)d_in[5];
    const float* b2  = (const float*)d_in[6];
    const float* g2  = (const float*)d_in[7];
    const float* be2 = (const float*)d_in[8];
    const float* W3  = (const float*)d_in[9];
    const float* b3  = (const float*)d_in[10];
    float* out = (float*)d_out;

    const int B   = in_sizes[0] / ZDIM;     // 4096
    const int nbc = B / BCHUNK;             // 256
    const int grid = (PDIM / PB) * nbc;     // 64 * 256 = 16384

    hipLaunchKernelGGL(pair_mlp_kernel, dim3(grid), dim3(PB), 0, stream,
                       x, W1, b1, g1, be1, W2, b2, g2, be2, W3, b3, out, nbc);
}